// Round 18
// baseline (138.088 us; speedup 1.0000x reference)
//
#include <hip/hip_runtime.h>

#define BATCH 8192
#define DIM 1024
#define HEADS 8
#define HEAD_DIM 128
#define DSTATE 256

typedef __attribute__((ext_vector_type(8))) short short8v;   // 8 bf16 (4 VGPRs)
typedef __attribute__((ext_vector_type(4))) float f32x4;
typedef __attribute__((ext_vector_type(4))) unsigned short ushort4v;
typedef __attribute__((ext_vector_type(4))) unsigned int uint4v;

__device__ __forceinline__ unsigned short f2bf(float x) {
  unsigned int u = __builtin_bit_cast(unsigned int, x);
  unsigned int r = u + 0x7FFFu + ((u >> 16) & 1u);   // RNE
  return (unsigned short)(r >> 16);
}
__device__ __forceinline__ float bf2f(unsigned short h) {
  unsigned int u = ((unsigned int)h) << 16;
  return __builtin_bit_cast(float, u);
}
__device__ __forceinline__ short8v pack8(const f32x4 a, const f32x4 b) {
  uint4v u;
  u[0] = (unsigned)f2bf(a[0]) | ((unsigned)f2bf(a[1]) << 16);
  u[1] = (unsigned)f2bf(a[2]) | ((unsigned)f2bf(a[3]) << 16);
  u[2] = (unsigned)f2bf(b[0]) | ((unsigned)f2bf(b[1]) << 16);
  u[3] = (unsigned)f2bf(b[2]) | ((unsigned)f2bf(b[3]) << 16);
  return __builtin_bit_cast(short8v, u);
}

// async global->LDS: dest = uniform LDS base + lane*size; source is PER-LANE.
__device__ __forceinline__ void stage16f(const float* g, float* l) {
  __builtin_amdgcn_global_load_lds(
      (const __attribute__((address_space(1))) unsigned int*)g,
      (__attribute__((address_space(3))) unsigned int*)l, 16, 0, 0);
}
__device__ __forceinline__ void stage4u(const unsigned short* g, unsigned short* l) {
  __builtin_amdgcn_global_load_lds(
      (const __attribute__((address_space(1))) unsigned int*)g,
      (__attribute__((address_space(3))) unsigned int*)l, 4, 0, 0);
}

#define BARRIER() do { \
  asm volatile("s_waitcnt lgkmcnt(0)" ::: "memory"); \
  __builtin_amdgcn_s_barrier(); \
  asm volatile("" ::: "memory"); } while (0)

// Row permutation (within each head): stored row s <-> true n.
//   s = 32j + 16t + 4g + r   <->   n = 32j + 8g + 4t + r
// GEMM1's MFMA output (rows s) lands exactly in GEMM2's B-operand layout.

// ---------- prep: x_hat bf16 (prescaled) + 1/scale only ----------
__global__ __launch_bounds__(256) void prep(
    const float* __restrict__ xtg,
    float* __restrict__ rscale, unsigned short* __restrict__ xhb) {
  const int wid = threadIdx.x >> 6, lane = threadIdx.x & 63;
  const int row = blockIdx.x * 4 + wid;
  const float* xr = xtg + (size_t)row * DIM;
  unsigned short* xo = xhb + (size_t)row * DIM;
  f32x4 v[4];
  float ssq = 0.f;
  #pragma unroll
  for (int c = 0; c < 4; ++c) {
    v[c] = *(const f32x4*)(xr + c * 256 + lane * 4);
    ssq += v[c][0]*v[c][0] + v[c][1]*v[c][1] + v[c][2]*v[c][2] + v[c][3]*v[c][3];
  }
  #pragma unroll
  for (int m = 1; m < 64; m <<= 1) ssq += __shfl_xor(ssq, m, 64);
  const float sc = rsqrtf(ssq * (1.0f / DIM) + 1e-4f);
  if (lane == 0) rscale[row] = 1.0f / sc;
  #pragma unroll
  for (int c = 0; c < 4; ++c) {
    ushort4v o;
    o[0] = f2bf(v[c][0] * sc); o[1] = f2bf(v[c][1] * sc);
    o[2] = f2bf(v[c][2] * sc); o[3] = f2bf(v[c][3] * sc);
    *(ushort4v*)(xo + c * 256 + lane * 4) = o;
  }
}

// ---------- main: persistent block, IN-PROLOGUE weight gen, 3-buf pipeline ----------
// Grid: 256 blocks = 32 row-groups x 8 heads (1 block/CU), 512 threads = 8 waves.
// Prologue: each wave generates its OWN W1/W2/A_bar register fragments from raw
// B/C/params (wn folded, permuted rows) — overlapped with STAGE(0)/STAGE(1).
// Wave w: GEMM1 n-window j=w (+ reg->global ns stores via shfl fixup),
// GEMM2 p-tile [16w,16w+16) with split accumulators (2x 8-deep MFMA chains).
// Iter t: vmcnt(N) -> BAR1 -> STAGE(t+2) -> PHASE1(t) -> BAR2 -> PHASE2(t).
__global__ __launch_bounds__(512, 2) void s5_main(
    const float* __restrict__ logdt, const float* __restrict__ arelog,
    const float* __restrict__ aim,
    const float* __restrict__ Bre, const float* __restrict__ Bim,
    const float* __restrict__ Cre, const float* __restrict__ Cim,
    const float* __restrict__ rscale, const unsigned short* __restrict__ xhb,
    const float* __restrict__ sre, const float* __restrict__ sim,
    const float* __restrict__ dvec, const float* __restrict__ normw,
    float* __restrict__ out, float* __restrict__ nsre, float* __restrict__ nsim) {
  __shared__ float Sb[3][2][16][256];                // 96 KB state tiles (read-only)
  __shared__ unsigned short xbL[3][16][128];         // 12 KB bf16 x_hat (swizzled)
  __shared__ unsigned short pf[2][8][64][8];         // 16 KB P exchange
  __shared__ float rsL[256];                         // 1 KB row 1/scales
  const int tid = threadIdx.x;
  const int w = tid >> 6, lane = tid & 63;
  const int g = lane >> 4, bl = lane & 15;
  const int h = blockIdx.x & 7;
  const int blkrow = (blockIdx.x >> 3) * 256;

  // ---- STAGE tile t: 6 uniform vm ops per wave ----
  auto STAGE = [&](int t) {
    const int b = t % 3;
    const int gr0 = blkrow + t * 16;
    #pragma unroll
    for (int i = 0; i < 2; ++i) {
      const int row = 2 * w + i;
      const size_t rb = ((size_t)(gr0 + row) * HEADS + h) * DSTATE;
      const int soff = (lane ^ (row & 7)) * 4;       // pre-swizzled source chunk
      stage16f(sre + rb + soff, &Sb[b][0][row][0]);
      stage16f(sim + rb + soff, &Sb[b][1][row][0]);
    }
    #pragma unroll
    for (int i = 0; i < 2; ++i) {
      const int row = 2 * w + i;                     // one 256B x_hat row per instr
      const unsigned short* src = xhb + (size_t)(gr0 + row) * DIM + h * HEAD_DIM
          + (((lane >> 2) ^ (row & 7)) << 3) + ((lane & 3) << 1);
      stage4u(src, &xbL[b][row][0]);
    }
  };

  // ---- issue stages FIRST so weight-gen overlaps the HBM latency ----
  if (w == 0) stage16f(rscale + blkrow + lane * 4, &rsL[0]);
  STAGE(0);
  STAGE(1);

  // ---- prologue: generate register-resident weights from raw params ----
  // W1 (wn-folded, permuted rows): chunk kk=2w+tt, stored row s=kk*16+bl ->
  //   n = 32w + ((bl>>2)&3)*8 + tt*4 + (bl&3)  (coef is per-n, constant over p)
  short8v w1r[2][4], w1i[2][4];
  #pragma unroll
  for (int tt = 0; tt < 2; ++tt) {
    const int n = 32 * w + ((bl >> 2) & 3) * 8 + tt * 4 + (bl & 3);
    const int hn = h * 256 + n;
    const float ld = logdt[hn];
    const float dtv = log1pf(expf(ld));              // softplus
    const float Ar = -expf(arelog[hn]);
    const float Ai = aim[hn];
    const float ee = expf(dtv * Ar), th = dtv * Ai;
    const float Abr = ee * cosf(th), Abi = ee * sinf(th);
    const float den = Ar * Ar + Ai * Ai;
    const float br_ = Abr - 1.0f;
    const float cr = (br_ * Ar + Abi * Ai) / den;
    const float ci = (Abi * Ar - br_ * Ai) / den;
    #pragma unroll
    for (int ks = 0; ks < 4; ++ks) {
      const size_t po = (size_t)hn * 128 + ks * 32 + g * 8;
      const f32x4 br0 = *(const f32x4*)(Bre + po);
      const f32x4 br1 = *(const f32x4*)(Bre + po + 4);
      const f32x4 bi0 = *(const f32x4*)(Bim + po);
      const f32x4 bi1 = *(const f32x4*)(Bim + po + 4);
      const int nwo = h * 128 + ks * 32 + g * 8;
      const f32x4 nw0 = *(const f32x4*)(normw + nwo);
      const f32x4 nw1 = *(const f32x4*)(normw + nwo + 4);
      f32x4 r0, r1, i0, i1;
      #pragma unroll
      for (int r = 0; r < 4; ++r) {
        r0[r] = (cr * br0[r] - ci * bi0[r]) * nw0[r];
        i0[r] = (cr * bi0[r] + ci * br0[r]) * nw0[r];
        r1[r] = (cr * br1[r] - ci * bi1[r]) * nw1[r];
        i1[r] = (cr * bi1[r] + ci * br1[r]) * nw1[r];
      }
      w1r[tt][ks] = pack8(r0, r1);
      w1i[tt][ks] = pack8(i0, i1);
    }
  }
  // W2 = C_re / -C_im at rows p=w*16+bl, cols j*32+g*8+[0..7]
  short8v w2r[8], w2i[8];
  #pragma unroll
  for (int j = 0; j < 8; ++j) {
    const size_t co = ((size_t)(h * 128 + w * 16 + bl)) * 256 + j * 32 + g * 8;
    const f32x4 c0 = *(const f32x4*)(Cre + co);
    const f32x4 c1 = *(const f32x4*)(Cre + co + 4);
    const f32x4 d0 = *(const f32x4*)(Cim + co);
    const f32x4 d1 = *(const f32x4*)(Cim + co + 4);
    f32x4 m0, m1;
    #pragma unroll
    for (int r = 0; r < 4; ++r) { m0[r] = -d0[r]; m1[r] = -d1[r]; }
    w2r[j] = pack8(c0, c1);
    w2i[j] = pack8(m0, m1);
  }
  // A_bar (permuted): reg element (tt,r) needs n = 32w + 8g + 4tt + r
  f32x4 Arh[2], Aih[2];
  #pragma unroll
  for (int tt = 0; tt < 2; ++tt) {
    const int nb = h * 256 + 32 * w + 8 * g + 4 * tt;
    const f32x4 ld4 = *(const f32x4*)(logdt + nb);
    const f32x4 ar4 = *(const f32x4*)(arelog + nb);
    const f32x4 ai4 = *(const f32x4*)(aim + nb);
    #pragma unroll
    for (int r = 0; r < 4; ++r) {
      const float dtv = log1pf(expf(ld4[r]));
      const float Ar = -expf(ar4[r]);
      const float Ai = ai4[r];
      const float ee = expf(dtv * Ar), th = dtv * Ai;
      Arh[tt][r] = ee * cosf(th);
      Aih[tt][r] = ee * sinf(th);
    }
  }
  f32x4 d4;                                          // D * norm_weight (folded)
  {
    const int col = h * HEAD_DIM + w * 16 + g * 4;
    const f32x4 dv = *(const f32x4*)(dvec + col);
    const f32x4 nv = *(const f32x4*)(normw + col);
    #pragma unroll
    for (int r = 0; r < 4; ++r) d4[r] = dv[r] * nv[r];
  }
  const int srcA = ((g >> 1) << 4) + bl;             // shfl sources, ns store fixup
  const int srcB = (((g >> 1) + 2) << 4) + bl;

  // ---- PHASE1(t): xf direct b128, GEMM1, recurrence, pf pack, ns stores ----
  auto PHASE1 = [&](int t) {
    const int b = t % 3;
    short8v xf[4];
    #pragma unroll
    for (int ks = 0; ks < 4; ++ks)
      xf[ks] = *(const short8v*)&xbL[b][bl][(((ks * 4 + g) ^ (bl & 7)) << 3)];
    f32x4 nre[2], nim[2];
    unsigned pr0 = 0, pr1 = 0, pi0 = 0, pi1 = 0;
    #pragma unroll
    for (int tt = 0; tt < 2; ++tt) {
      f32x4 dr = {0.f,0.f,0.f,0.f};
      f32x4 di = {0.f,0.f,0.f,0.f};
      #pragma unroll
      for (int ks = 0; ks < 4; ++ks)
        dr = __builtin_amdgcn_mfma_f32_16x16x32_bf16(w1r[tt][ks], xf[ks], dr, 0, 0, 0);
      #pragma unroll
      for (int ks = 0; ks < 4; ++ks)
        di = __builtin_amdgcn_mfma_f32_16x16x32_bf16(w1i[tt][ks], xf[ks], di, 0, 0, 0);
      const int c = (((8 * w + 2 * g + tt) ^ (bl & 7)) << 2);
      const f32x4 s_r = *(const f32x4*)&Sb[b][0][bl][c];
      const f32x4 s_i = *(const f32x4*)&Sb[b][1][bl][c];
      f32x4 nr, ni;
      #pragma unroll
      for (int r = 0; r < 4; ++r) {
        nr[r] = fmaf(Arh[tt][r], s_r[r], fmaf(-Aih[tt][r], s_i[r], dr[r]));
        ni[r] = fmaf(Arh[tt][r], s_i[r], fmaf(Aih[tt][r], s_r[r], di[r]));
      }
      nre[tt] = nr; nim[tt] = ni;
      unsigned lo  = (unsigned)f2bf(nr[0]) | ((unsigned)f2bf(nr[1]) << 16);
      unsigned hi  = (unsigned)f2bf(nr[2]) | ((unsigned)f2bf(nr[3]) << 16);
      unsigned lo2 = (unsigned)f2bf(ni[0]) | ((unsigned)f2bf(ni[1]) << 16);
      unsigned hi2 = (unsigned)f2bf(ni[2]) | ((unsigned)f2bf(ni[3]) << 16);
      if (tt == 0) { pr0 = lo; pr1 = hi; pi0 = lo2; pi1 = hi2; }
      else {
        uint4v urv; urv[0] = pr0; urv[1] = pr1; urv[2] = lo;  urv[3] = hi;
        uint4v uiv; uiv[0] = pi0; uiv[1] = pi1; uiv[2] = lo2; uiv[3] = hi2;
        *(short8v*)&pf[0][w][lane][0] = __builtin_bit_cast(short8v, urv);
        *(short8v*)&pf[1][w][lane][0] = __builtin_bit_cast(short8v, uiv);
      }
    }
    // shfl fix-up -> per-instruction 64B-contiguous-per-row ns stores (amp-free)
    f32x4 v1r, v2r, v1i, v2i;
    #pragma unroll
    for (int e = 0; e < 4; ++e) {
      float a1 = __shfl(nre[0][e], srcA, 64);
      float b1 = __shfl(nre[1][e], srcA, 64);
      v1r[e] = (g & 1) ? b1 : a1;
      float a2 = __shfl(nre[0][e], srcB, 64);
      float b2 = __shfl(nre[1][e], srcB, 64);
      v2r[e] = (g & 1) ? b2 : a2;
      float c1 = __shfl(nim[0][e], srcA, 64);
      float d1 = __shfl(nim[1][e], srcA, 64);
      v1i[e] = (g & 1) ? d1 : c1;
      float c2 = __shfl(nim[0][e], srcB, 64);
      float d2 = __shfl(nim[1][e], srcB, 64);
      v2i[e] = (g & 1) ? d2 : c2;
    }
    const size_t no = ((size_t)(blkrow + t * 16 + bl) * HEADS + h) * DSTATE + w * 32 + g * 4;
    *(f32x4*)(nsre + no)      = v1r;
    *(f32x4*)(nsre + no + 16) = v2r;
    *(f32x4*)(nsim + no)      = v1i;
    *(f32x4*)(nsim + no + 16) = v2i;
  };

  // ---- PHASE2(t): GEMM2 p-tile from pf (split 8-deep chains), epilogue ----
  auto PHASE2 = [&](int t) {
    const int b = t % 3;
    f32x4 a2 = {0.f,0.f,0.f,0.f};
    f32x4 a2b = {0.f,0.f,0.f,0.f};
    #pragma unroll
    for (int jj = 0; jj < 4; ++jj) {
      const int j0 = 2 * jj, j1 = 2 * jj + 1;
      const short8v pbr0 = *(const short8v*)&pf[0][j0][lane][0];
      const short8v pbi0 = *(const short8v*)&pf[1][j0][lane][0];
      const short8v pbr1 = *(const short8v*)&pf[0][j1][lane][0];
      const short8v pbi1 = *(const short8v*)&pf[1][j1][lane][0];
      a2  = __builtin_amdgcn_mfma_f32_16x16x32_bf16(w2r[j0], pbr0, a2, 0, 0, 0);
      a2b = __builtin_amdgcn_mfma_f32_16x16x32_bf16(w2r[j1], pbr1, a2b, 0, 0, 0);
      a2  = __builtin_amdgcn_mfma_f32_16x16x32_bf16(w2i[j0], pbi0, a2, 0, 0, 0);
      a2b = __builtin_amdgcn_mfma_f32_16x16x32_bf16(w2i[j1], pbi1, a2b, 0, 0, 0);
    }
    const float rs = rsL[t * 16 + bl];
    const int col = h * HEAD_DIM + w * 16 + g * 4;
    const size_t o = (size_t)(blkrow + t * 16 + bl) * DIM + col;
    // x_hat col = w*16+g*4 -> chunk (2w+(g>>1))^(bl&7), intra-offset (g&1)*4
    const unsigned short* xp =
        &xbL[b][bl][(((2 * w + (g >> 1)) ^ (bl & 7)) << 3) + ((g & 1) << 2)];
    f32x4 ro;
    #pragma unroll
    for (int r = 0; r < 4; ++r)
      ro[r] = bf2f(xp[r]) * (rs + d4[r]) + 2.0f * (a2[r] + a2b[r]);
    *(f32x4*)(out + o) = ro;
  };

  for (int t = 0; t < 16; ++t) {
    if (t == 0)       asm volatile("s_waitcnt vmcnt(6)"  ::: "memory");
    else if (t == 1)  asm volatile("s_waitcnt vmcnt(11)" ::: "memory");
    else if (t <= 14) asm volatile("s_waitcnt vmcnt(16)" ::: "memory");
    else              asm volatile("s_waitcnt vmcnt(10)" ::: "memory");
    BARRIER();                                       // stage(t) visible; pf free
    if (t + 2 < 16) STAGE(t + 2);
    __builtin_amdgcn_sched_barrier(0);               // pin vm issue order
    PHASE1(t);
    BARRIER();                                       // pf complete
    PHASE2(t);
  }
}

extern "C" void kernel_launch(void* const* d_in, const int* in_sizes, int n_in,
                              void* d_out, int out_size, void* d_ws, size_t ws_size,
                              hipStream_t stream) {
  const float* x_t      = (const float*)d_in[0];
  const float* state_re = (const float*)d_in[1];
  const float* state_im = (const float*)d_in[2];
  const float* norm_w   = (const float*)d_in[3];
  const float* A_re_log = (const float*)d_in[4];
  const float* A_im     = (const float*)d_in[5];
  const float* B_re     = (const float*)d_in[6];
  const float* B_im     = (const float*)d_in[7];
  const float* C_re     = (const float*)d_in[8];
  const float* C_im     = (const float*)d_in[9];
  const float* Dv       = (const float*)d_in[10];
  const float* log_dt   = (const float*)d_in[11];

  float* out   = (float*)d_out;
  float* ns_re = out + (size_t)BATCH * DIM;
  float* ns_im = ns_re + (size_t)BATCH * HEADS * DSTATE;

  char* ws = (char*)d_ws;
  float* rscale = (float*)ws;                                       // 32 KB
  unsigned short* xhb = (unsigned short*)(rscale + 8192);           // 16.8 MB bf16 x_hat

  prep<<<2048, 256, 0, stream>>>(x_t, rscale, xhb);
  s5_main<<<256, 512, 0, stream>>>(log_dt, A_re_log, A_im, B_re, B_im, C_re, C_im,
                                   rscale, xhb, state_re, state_im, Dv, norm_w,
                                   out, ns_re, ns_im);
}

// Round 19
// 89.336 us; speedup vs baseline: 1.5457x; 1.5457x over previous
//
#include <hip/hip_runtime.h>

#define BATCH 8192
#define DIM 1024
#define HEADS 8
#define HEAD_DIM 128
#define DSTATE 256

typedef __attribute__((ext_vector_type(8))) short short8v;   // 8 bf16 (4 VGPRs)
typedef __attribute__((ext_vector_type(4))) float f32x4;
typedef __attribute__((ext_vector_type(4))) unsigned short ushort4v;
typedef __attribute__((ext_vector_type(4))) unsigned int uint4v;

__device__ __forceinline__ unsigned short f2bf(float x) {
  unsigned int u = __builtin_bit_cast(unsigned int, x);
  unsigned int r = u + 0x7FFFu + ((u >> 16) & 1u);   // RNE
  return (unsigned short)(r >> 16);
}
__device__ __forceinline__ float bf2f(unsigned short h) {
  unsigned int u = ((unsigned int)h) << 16;
  return __builtin_bit_cast(float, u);
}

// async global->LDS: dest = uniform LDS base + lane*size; source is PER-LANE.
__device__ __forceinline__ void stage16f(const float* g, float* l) {
  __builtin_amdgcn_global_load_lds(
      (const __attribute__((address_space(1))) unsigned int*)g,
      (__attribute__((address_space(3))) unsigned int*)l, 16, 0, 0);
}
__device__ __forceinline__ void stage4u(const unsigned short* g, unsigned short* l) {
  __builtin_amdgcn_global_load_lds(
      (const __attribute__((address_space(1))) unsigned int*)g,
      (__attribute__((address_space(3))) unsigned int*)l, 4, 0, 0);
}

#define BARRIER() do { \
  asm volatile("s_waitcnt lgkmcnt(0)" ::: "memory"); \
  __builtin_amdgcn_s_barrier(); \
  asm volatile("" ::: "memory"); } while (0)

// Row permutation (within each head): stored row s <-> true n.
//   s = 32j + 16t + 4g + r   <->   n = 32j + 8g + 4t + r
// GEMM1's MFMA output (rows s) lands exactly in GEMM2's B-operand layout.

// ---------- prep: W1 (wn-folded, permuted) + A_bar + W2 + x_hat bf16 + 1/scale ----------
__global__ __launch_bounds__(256) void prep(
    const float* __restrict__ logdt, const float* __restrict__ arelog,
    const float* __restrict__ aim,
    const float* __restrict__ Bre, const float* __restrict__ Bim,
    const float* __restrict__ Cre, const float* __restrict__ Cim,
    const float* __restrict__ xtg, const float* __restrict__ normw,
    unsigned short* __restrict__ w1re, unsigned short* __restrict__ w1im,
    unsigned short* __restrict__ w2re, unsigned short* __restrict__ w2mi,
    float* __restrict__ abr, float* __restrict__ abi,
    float* __restrict__ rscale, unsigned short* __restrict__ xhb) {
  const int blk = blockIdx.x;
  if (blk < 1024) {
    const int i = blk * 256 + threadIdx.x;           // h*32768 + s*128 + p
    const int p = i & 127, s = (i >> 7) & 255, h = i >> 15;
    const int kk = s >> 4, u = s & 15;
    const int n = ((kk >> 1) << 5) + ((u >> 2) & 3) * 8 + (kk & 1) * 4 + (u & 3);
    const int hn = h * 256 + n;
    const float ld = logdt[hn];
    const float dt = log1pf(expf(ld));               // softplus
    const float Ar = -expf(arelog[hn]);
    const float Ai = aim[hn];
    const float e = expf(dt * Ar), th = dt * Ai;
    const float Abr = e * cosf(th), Abi = e * sinf(th);
    if (p == 0) { abr[h * 256 + s] = Abr; abi[h * 256 + s] = Abi; }
    const float den = Ar * Ar + Ai * Ai;
    const float br_ = Abr - 1.0f;
    const float cr = (br_ * Ar + Abi * Ai) / den;
    const float ci = (Abi * Ar - br_ * Ai) / den;
    const int src = hn * 128 + p;
    const float wb = normw[h * 128 + p];             // fold norm weight into W1
    const float bre = Bre[src], bim = Bim[src];
    w1re[i] = f2bf((cr * bre - ci * bim) * wb);
    w1im[i] = f2bf((cr * bim + ci * bre) * wb);
  } else if (blk < 2048) {
    const int i = (blk - 1024) * 256 + threadIdx.x;  // 262144 = H*P*N
    w2re[i] = f2bf(Cre[i]);
    w2mi[i] = f2bf(-Cim[i]);
  } else {
    const int wid = threadIdx.x >> 6, lane = threadIdx.x & 63;
    const int row = (blk - 2048) * 4 + wid;
    const float* xr = xtg + (size_t)row * DIM;
    unsigned short* xo = xhb + (size_t)row * DIM;
    f32x4 v[4];
    float ssq = 0.f;
    #pragma unroll
    for (int c = 0; c < 4; ++c) {
      v[c] = *(const f32x4*)(xr + c * 256 + lane * 4);
      ssq += v[c][0]*v[c][0] + v[c][1]*v[c][1] + v[c][2]*v[c][2] + v[c][3]*v[c][3];
    }
    #pragma unroll
    for (int m = 1; m < 64; m <<= 1) ssq += __shfl_xor(ssq, m, 64);
    const float sc = rsqrtf(ssq * (1.0f / DIM) + 1e-4f);
    if (lane == 0) rscale[row] = 1.0f / sc;
    #pragma unroll
    for (int c = 0; c < 4; ++c) {
      ushort4v o;
      o[0] = f2bf(v[c][0] * sc); o[1] = f2bf(v[c][1] * sc);
      o[2] = f2bf(v[c][2] * sc); o[3] = f2bf(v[c][3] * sc);
      *(ushort4v*)(xo + c * 256 + lane * 4) = o;
    }
  }
}

// ---------- main: persistent block, reg weights, 3-buf 2-deep pipeline ----------
// Grid: 256 blocks = 32 row-groups x 8 heads (1 block/CU), 512 threads = 8 waves.
// Wave w: GEMM1 n-window j=w (+ direct reg->global ns store via shfl fixup),
// GEMM2 p-tile [16w,16w+16) with SPLIT accumulators (2x 8-deep MFMA chains).
// Iter t: vmcnt(N) -> BAR1 -> STAGE(t+2) -> PHASE1(t) -> BAR2 -> PHASE2(t).
__global__ __launch_bounds__(512, 2) void s5_main(
    const unsigned short* __restrict__ w1re, const unsigned short* __restrict__ w1im,
    const unsigned short* __restrict__ w2re, const unsigned short* __restrict__ w2mi,
    const float* __restrict__ abrp, const float* __restrict__ abip,
    const float* __restrict__ rscale, const unsigned short* __restrict__ xhb,
    const float* __restrict__ sre, const float* __restrict__ sim,
    const float* __restrict__ dvec, const float* __restrict__ normw,
    float* __restrict__ out, float* __restrict__ nsre, float* __restrict__ nsim) {
  __shared__ float Sb[3][2][16][256];                // 96 KB state tiles (read-only)
  __shared__ unsigned short xbL[3][16][128];         // 12 KB bf16 x_hat (swizzled)
  __shared__ unsigned short pf[2][8][64][8];         // 16 KB P exchange
  __shared__ float rsL[256];                         // 1 KB row 1/scales
  const int tid = threadIdx.x;
  const int w = tid >> 6, lane = tid & 63;
  const int g = lane >> 4, bl = lane & 15;
  const int h = blockIdx.x & 7;
  const int blkrow = (blockIdx.x >> 3) * 256;

  // ---- persistent weights -> registers (once per block) ----
  short8v w1r[2][4], w1i[2][4];
  #pragma unroll
  for (int t = 0; t < 2; ++t) {
    const int kk = 2 * w + t;
    const unsigned short* pr = w1re + ((size_t)(h * DSTATE + kk * 16 + bl)) * HEAD_DIM + g * 8;
    const unsigned short* pi = w1im + ((size_t)(h * DSTATE + kk * 16 + bl)) * HEAD_DIM + g * 8;
    #pragma unroll
    for (int ks = 0; ks < 4; ++ks) {
      w1r[t][ks] = *(const short8v*)(pr + ks * 32);
      w1i[t][ks] = *(const short8v*)(pi + ks * 32);
    }
  }
  short8v w2r[8], w2i[8];
  {
    const unsigned short* qr = w2re + ((size_t)(h * HEAD_DIM + w * 16 + bl)) * DSTATE + g * 8;
    const unsigned short* qi = w2mi + ((size_t)(h * HEAD_DIM + w * 16 + bl)) * DSTATE + g * 8;
    #pragma unroll
    for (int j = 0; j < 8; ++j) {
      w2r[j] = *(const short8v*)(qr + j * 32);
      w2i[j] = *(const short8v*)(qi + j * 32);
    }
  }
  f32x4 Arh[2], Aih[2];
  #pragma unroll
  for (int t = 0; t < 2; ++t) {
    Arh[t] = *(const f32x4*)(abrp + h * DSTATE + (2 * w + t) * 16 + g * 4);
    Aih[t] = *(const f32x4*)(abip + h * DSTATE + (2 * w + t) * 16 + g * 4);
  }
  f32x4 d4;                                          // D * norm_weight (folded)
  {
    const int col = h * HEAD_DIM + w * 16 + g * 4;
    const f32x4 dv = *(const f32x4*)(dvec + col);
    const f32x4 nv = *(const f32x4*)(normw + col);
    #pragma unroll
    for (int r = 0; r < 4; ++r) d4[r] = dv[r] * nv[r];
  }
  const int srcA = ((g >> 1) << 4) + bl;             // shfl sources, ns store fixup
  const int srcB = (((g >> 1) + 2) << 4) + bl;

  // ---- STAGE tile t: 6 uniform vm ops per wave ----
  auto STAGE = [&](int t) {
    const int b = t % 3;
    const int gr0 = blkrow + t * 16;
    #pragma unroll
    for (int i = 0; i < 2; ++i) {
      const int row = 2 * w + i;
      const size_t rb = ((size_t)(gr0 + row) * HEADS + h) * DSTATE;
      const int soff = (lane ^ (row & 7)) * 4;       // pre-swizzled source chunk
      stage16f(sre + rb + soff, &Sb[b][0][row][0]);
      stage16f(sim + rb + soff, &Sb[b][1][row][0]);
    }
    #pragma unroll
    for (int i = 0; i < 2; ++i) {
      const int row = 2 * w + i;                     // one 256B x_hat row per instr
      const unsigned short* src = xhb + (size_t)(gr0 + row) * DIM + h * HEAD_DIM
          + (((lane >> 2) ^ (row & 7)) << 3) + ((lane & 3) << 1);
      stage4u(src, &xbL[b][row][0]);
    }
  };

  // ---- PHASE1(t): xf direct b128, GEMM1, recurrence, pf pack, ns stores ----
  auto PHASE1 = [&](int t) {
    const int b = t % 3;
    short8v xf[4];
    #pragma unroll
    for (int ks = 0; ks < 4; ++ks)
      xf[ks] = *(const short8v*)&xbL[b][bl][(((ks * 4 + g) ^ (bl & 7)) << 3)];
    f32x4 nre[2], nim[2];
    unsigned pr0 = 0, pr1 = 0, pi0 = 0, pi1 = 0;
    #pragma unroll
    for (int tt = 0; tt < 2; ++tt) {
      f32x4 dr = {0.f,0.f,0.f,0.f};
      f32x4 di = {0.f,0.f,0.f,0.f};
      #pragma unroll
      for (int ks = 0; ks < 4; ++ks)
        dr = __builtin_amdgcn_mfma_f32_16x16x32_bf16(w1r[tt][ks], xf[ks], dr, 0, 0, 0);
      #pragma unroll
      for (int ks = 0; ks < 4; ++ks)
        di = __builtin_amdgcn_mfma_f32_16x16x32_bf16(w1i[tt][ks], xf[ks], di, 0, 0, 0);
      const int c = (((8 * w + 2 * g + tt) ^ (bl & 7)) << 2);
      const f32x4 s_r = *(const f32x4*)&Sb[b][0][bl][c];
      const f32x4 s_i = *(const f32x4*)&Sb[b][1][bl][c];
      f32x4 nr, ni;
      #pragma unroll
      for (int r = 0; r < 4; ++r) {
        nr[r] = fmaf(Arh[tt][r], s_r[r], fmaf(-Aih[tt][r], s_i[r], dr[r]));
        ni[r] = fmaf(Arh[tt][r], s_i[r], fmaf(Aih[tt][r], s_r[r], di[r]));
      }
      nre[tt] = nr; nim[tt] = ni;
      unsigned lo  = (unsigned)f2bf(nr[0]) | ((unsigned)f2bf(nr[1]) << 16);
      unsigned hi  = (unsigned)f2bf(nr[2]) | ((unsigned)f2bf(nr[3]) << 16);
      unsigned lo2 = (unsigned)f2bf(ni[0]) | ((unsigned)f2bf(ni[1]) << 16);
      unsigned hi2 = (unsigned)f2bf(ni[2]) | ((unsigned)f2bf(ni[3]) << 16);
      if (tt == 0) { pr0 = lo; pr1 = hi; pi0 = lo2; pi1 = hi2; }
      else {
        uint4v urv; urv[0] = pr0; urv[1] = pr1; urv[2] = lo;  urv[3] = hi;
        uint4v uiv; uiv[0] = pi0; uiv[1] = pi1; uiv[2] = lo2; uiv[3] = hi2;
        *(short8v*)&pf[0][w][lane][0] = __builtin_bit_cast(short8v, urv);
        *(short8v*)&pf[1][w][lane][0] = __builtin_bit_cast(short8v, uiv);
      }
    }
    // shfl fix-up -> per-instruction 64B-contiguous-per-row ns stores (amp-free)
    f32x4 v1r, v2r, v1i, v2i;
    #pragma unroll
    for (int e = 0; e < 4; ++e) {
      float a1 = __shfl(nre[0][e], srcA, 64);
      float b1 = __shfl(nre[1][e], srcA, 64);
      v1r[e] = (g & 1) ? b1 : a1;
      float a2 = __shfl(nre[0][e], srcB, 64);
      float b2 = __shfl(nre[1][e], srcB, 64);
      v2r[e] = (g & 1) ? b2 : a2;
      float c1 = __shfl(nim[0][e], srcA, 64);
      float d1 = __shfl(nim[1][e], srcA, 64);
      v1i[e] = (g & 1) ? d1 : c1;
      float c2 = __shfl(nim[0][e], srcB, 64);
      float d2 = __shfl(nim[1][e], srcB, 64);
      v2i[e] = (g & 1) ? d2 : c2;
    }
    const size_t no = ((size_t)(blkrow + t * 16 + bl) * HEADS + h) * DSTATE + w * 32 + g * 4;
    *(f32x4*)(nsre + no)      = v1r;
    *(f32x4*)(nsre + no + 16) = v2r;
    *(f32x4*)(nsim + no)      = v1i;
    *(f32x4*)(nsim + no + 16) = v2i;
  };

  // ---- PHASE2(t): GEMM2 p-tile from pf (split 8-deep chains), epilogue ----
  auto PHASE2 = [&](int t) {
    const int b = t % 3;
    f32x4 a2 = {0.f,0.f,0.f,0.f};
    f32x4 a2b = {0.f,0.f,0.f,0.f};
    #pragma unroll
    for (int jj = 0; jj < 4; ++jj) {
      const int j0 = 2 * jj, j1 = 2 * jj + 1;
      const short8v pbr0 = *(const short8v*)&pf[0][j0][lane][0];
      const short8v pbi0 = *(const short8v*)&pf[1][j0][lane][0];
      const short8v pbr1 = *(const short8v*)&pf[0][j1][lane][0];
      const short8v pbi1 = *(const short8v*)&pf[1][j1][lane][0];
      a2  = __builtin_amdgcn_mfma_f32_16x16x32_bf16(w2r[j0], pbr0, a2, 0, 0, 0);
      a2b = __builtin_amdgcn_mfma_f32_16x16x32_bf16(w2r[j1], pbr1, a2b, 0, 0, 0);
      a2  = __builtin_amdgcn_mfma_f32_16x16x32_bf16(w2i[j0], pbi0, a2, 0, 0, 0);
      a2b = __builtin_amdgcn_mfma_f32_16x16x32_bf16(w2i[j1], pbi1, a2b, 0, 0, 0);
    }
    const float rs = rsL[t * 16 + bl];
    const int col = h * HEAD_DIM + w * 16 + g * 4;
    const size_t o = (size_t)(blkrow + t * 16 + bl) * DIM + col;
    // x_hat col = w*16+g*4 -> chunk (2w+(g>>1))^(bl&7), intra-offset (g&1)*4
    const unsigned short* xp =
        &xbL[b][bl][(((2 * w + (g >> 1)) ^ (bl & 7)) << 3) + ((g & 1) << 2)];
    f32x4 ro;
    #pragma unroll
    for (int r = 0; r < 4; ++r)
      ro[r] = bf2f(xp[r]) * (rs + d4[r]) + 2.0f * (a2[r] + a2b[r]);
    *(f32x4*)(out + o) = ro;
  };

  // ---- prologue: rsL (wave 0, oldest op so vm counts stay valid) ----
  if (w == 0) stage16f(rscale + blkrow + lane * 4, &rsL[0]);
  STAGE(0);
  STAGE(1);

  for (int t = 0; t < 16; ++t) {
    if (t == 0)       asm volatile("s_waitcnt vmcnt(6)"  ::: "memory");
    else if (t == 1)  asm volatile("s_waitcnt vmcnt(11)" ::: "memory");
    else if (t <= 14) asm volatile("s_waitcnt vmcnt(16)" ::: "memory");
    else              asm volatile("s_waitcnt vmcnt(10)" ::: "memory");
    BARRIER();                                       // stage(t) visible; pf free
    if (t + 2 < 16) STAGE(t + 2);
    __builtin_amdgcn_sched_barrier(0);               // pin vm issue order
    PHASE1(t);
    BARRIER();                                       // pf complete
    PHASE2(t);
  }
}

extern "C" void kernel_launch(void* const* d_in, const int* in_sizes, int n_in,
                              void* d_out, int out_size, void* d_ws, size_t ws_size,
                              hipStream_t stream) {
  const float* x_t      = (const float*)d_in[0];
  const float* state_re = (const float*)d_in[1];
  const float* state_im = (const float*)d_in[2];
  const float* norm_w   = (const float*)d_in[3];
  const float* A_re_log = (const float*)d_in[4];
  const float* A_im     = (const float*)d_in[5];
  const float* B_re     = (const float*)d_in[6];
  const float* B_im     = (const float*)d_in[7];
  const float* C_re     = (const float*)d_in[8];
  const float* C_im     = (const float*)d_in[9];
  const float* Dv       = (const float*)d_in[10];
  const float* log_dt   = (const float*)d_in[11];

  float* out   = (float*)d_out;
  float* ns_re = out + (size_t)BATCH * DIM;
  float* ns_im = ns_re + (size_t)BATCH * HEADS * DSTATE;

  char* ws = (char*)d_ws;
  unsigned short* w1re = (unsigned short*)ws;                       // 512 KB each
  unsigned short* w1im = w1re + 262144;
  unsigned short* w2re = w1im + 262144;
  unsigned short* w2mi = w2re + 262144;
  float* abr    = (float*)(ws + 4 * 524288);
  float* abi    = abr + 2048;
  float* rscale = abi + 2048;                                       // 8192 f32
  unsigned short* xhb = (unsigned short*)(rscale + 8192);           // 16.8 MB bf16 x_hat

  prep<<<4096, 256, 0, stream>>>(log_dt, A_re_log, A_im, B_re, B_im, C_re, C_im,
                                 x_t, norm_w, w1re, w1im, w2re, w2mi,
                                 abr, abi, rscale, xhb);
  s5_main<<<256, 512, 0, stream>>>(w1re, w1im, w2re, w2mi, abr, abi, rscale, xhb,
                                   state_re, state_im, Dv, norm_w,
                                   out, ns_re, ns_im);
}